// Round 8
// baseline (216.263 us; speedup 1.0000x reference)
//
#include <hip/hip_runtime.h>
#include <hip/hip_fp16.h>
#include <stdint.h>

#define B_  8
#define S_  2048
#define D_  512
#define K_  4096
#define N_  (B_ * S_)          // 16384 rows
#define NCB (K_ / 128)         // 32 code-blocks
#define NKB32 (D_ / 32)        // 16 k-blocks
#define MARGIN 0.014f          // 6sigma approx err + 127*ulp(512) key quantization

typedef _Float16 half8  __attribute__((ext_vector_type(8)));
typedef float    floatx4 __attribute__((ext_vector_type(4)));

// ---- workspace layout (bytes) ----
#define OFF_PK   0                                   // [N_][32] uint2 packed top-2 (4 MB)
#define OFF_EN   (OFF_PK + (size_t)N_ * NCB * 8)     // enorm [K_]
#define OFF_ZN   (OFF_EN + K_ * 4)                   // znorm [N_]
#define OFF_CNT  (OFF_ZN + N_ * 4)                   // counts [K_]
#define OFF_BL   (OFF_CNT + K_ * 4)                  // blockLoss [4096]
#define OFF_ZH   (OFF_BL + 4096 * 4)                 // zh packed [16][N_][32] f16 (16 MB)
#define OFF_EH   (OFF_ZH + (size_t)N_ * D_ * 2)     // eh packed [16][K_][32] f16 (4 MB)

__device__ __forceinline__ uint32_t umin32(uint32_t a, uint32_t b) { return a < b ? a : b; }
__device__ __forceinline__ uint32_t umax32(uint32_t a, uint32_t b) { return a > b ? a : b; }
__device__ __forceinline__ bool lexlt(float va, int ia, float vb, int ib) {
    return va < vb || (va == vb && ia < ib);
}

// async 16B global->LDS DMA; lds dst must be wave-uniform base + lane*16
__device__ __forceinline__ void load_lds16(const _Float16* g, _Float16* l) {
    __builtin_amdgcn_global_load_lds(
        (const __attribute__((address_space(1))) unsigned int*)(uintptr_t)g,
        (__attribute__((address_space(3))) unsigned int*)(uintptr_t)l,
        16, 0, 0);
}

// ---------------- kernel 1: fused prep (round-0 verbatim) ----------------
//  (a) row norms (order BIT-IDENTICAL across rounds -> preserves fp32 lattice),
//  (b) fp32->fp16 hi split, packed K-block-major + XOR chunk swizzle
//      (codebook scaled by 64, exact), (c) zero the histogram counts.
__global__ __launch_bounds__(256)
void vq_prep_kernel(const float* __restrict__ z, const float* __restrict__ cb,
                    _Float16* __restrict__ zh, _Float16* __restrict__ eh,
                    float* __restrict__ znorm, float* __restrict__ enorm,
                    int* __restrict__ counts) {
    const int t = threadIdx.x;
    if (blockIdx.x < 16) counts[blockIdx.x * 256 + t] = 0;

    const size_t u = (size_t)blockIdx.x * 256 + t;
    const int c   = (int)(u & 63);     // lane / chunk id (8 consecutive k)
    const int row = (int)(u >> 6);
    const bool isZ = row < N_;
    const int n = isZ ? row : row - N_;
    const float* r = (isZ ? z : cb) + (size_t)n * D_;

    // (a) norm — identical order across rounds
    float s = 0.f;
    for (int j = c; j < D_; j += 64) { float v = r[j]; s += v * v; }
    #pragma unroll
    for (int m = 1; m < 64; m <<= 1) s += __shfl_xor(s, m, 64);
    if (c == 0) { if (isZ) znorm[n] = s; else enorm[n] = s; }

    // (b) hi split
    const float scale = isZ ? 1.0f : 64.0f;
    const float4 v0 = *(const float4*)(r + c * 8);
    const float4 v1 = *(const float4*)(r + c * 8 + 4);
    float a[8] = {v0.x, v0.y, v0.z, v0.w, v1.x, v1.y, v1.z, v1.w};
    half8 h;
    #pragma unroll
    for (int j = 0; j < 8; j++) h[j] = (_Float16)(a[j] * scale);
    const int kb = c >> 2, qd = c & 3;
    const int sw = qd ^ ((n >> 1) & 3);
    const size_t rows = isZ ? (size_t)N_ : (size_t)K_;
    const size_t off = (size_t)kb * rows * 32 + (size_t)n * 32 + (size_t)(sw << 3);
    *(half8*)((isZ ? zh : eh) + off) = h;
}

// ---------------- kernel 2: 256x256-tile 16-wave dist GEMM + packed top-2 ----------------
// Diagnosis r0-r7: MfmaUtil pinned at 30-33% across ALL sync structures (lockstep,
// BK=64, 8-phase, barrier-free) => not schedule-bound; L2-traffic-bound at
// 65 FLOP/B (1 GB of L2 traffic for 68.7 GFLOP). Fix: 2x arithmetic intensity via
// 256x256 tile at UNCHANGED per-wave cost: 16 waves in a 4x4 grid, each wave owns
// 64x64 = acc[4][4] (64 VGPR + 64 AGPR = 128 = 4 waves/SIMD, same as r0; unlike
// r1's failed acc[8][4] 2-waves/SIMD version). L2 traffic: 1024 blocks x 512KB =
// 512MB (131 FLOP/B). Same r0 loop structure; per-(row,code) MFMA operands,
// K-order, keys, reduction, and merge are value-identical -> pK bit-identical.
__global__ __launch_bounds__(1024, 1)
void vq_dist_kernel(const _Float16* __restrict__ zh, const _Float16* __restrict__ eh,
                    const float* __restrict__ enorm, const float* __restrict__ znorm,
                    uint2* __restrict__ pK) {
    __shared__ __align__(16) _Float16 sA[2][8192];   // 256 rows x 32 k, double-buffered (32 KB)
    __shared__ float sE[256], sZn[256];
    __shared__ uint2 cK[4][256];                     // per wave-col top-2, 8 KB

    const int t  = threadIdx.x;                      // 0..1023
    const int c0 = blockIdx.x * 256;   // x = c-fast: eh stays L2-resident
    const int m0 = blockIdx.y * 256;

    if (t < 256) { sE[t] = enorm[c0 + t]; sZn[t] = znorm[m0 + t]; }

    const int lane = t & 63, wid = t >> 6;           // 16 waves
    const int wrow = wid & 3, wcol = wid >> 2;       // 4x4 wave grid, 64x64 each
    const int qd = lane >> 4, nl = lane & 15;
    const int sw8 = (qd ^ ((nl >> 1) & 3)) << 3;

    const size_t strideA = (size_t)N_ * 32;
    const size_t strideB = (size_t)K_ * 32;
    // A staging: 1024 threads x 16B = 16KB = full 256-row kb-plane per instruction
    const _Float16* gsrc = zh + (size_t)m0 * 32 + (size_t)t * 8;
    const _Float16* bptr = eh + (size_t)c0 * 32 + (size_t)((wcol * 64 + nl) * 32 + sw8);
    const int aoff = (wrow * 64 + nl) * 32 + sw8;

    floatx4 acc[4][4];
    #pragma unroll
    for (int i = 0; i < 4; i++)
        #pragma unroll
        for (int j = 0; j < 4; j++) acc[i][j] = (floatx4)0.f;

    load_lds16(gsrc, sA[0] + t * 8);   // stage kb=0

    for (int kb = 0; kb < NKB32; kb++) {
        __syncthreads();   // drains vmcnt: A(kb) landed; buf (kb+1)&1 free

        const _Float16* bp = bptr + (size_t)kb * strideB;
        half8 b_h[4];
        #pragma unroll
        for (int s = 0; s < 4; s++)
            b_h[s] = *(const half8*)(bp + s * 512);
        if (kb + 1 < NKB32)
            load_lds16(gsrc + (size_t)(kb + 1) * strideA, sA[(kb + 1) & 1] + t * 8);
        const _Float16* ah = sA[kb & 1] + aoff;
        half8 a_h[4];
        #pragma unroll
        for (int s = 0; s < 4; s++)
            a_h[s] = *(const half8*)(ah + s * 512);
        #pragma unroll
        for (int i = 0; i < 4; i++)
            #pragma unroll
            for (int j = 0; j < 4; j++)
                acc[i][j] = __builtin_amdgcn_mfma_f32_16x16x32_f16(a_h[i], b_h[j], acc[i][j], 0, 0, 0);
    }

    // epilogue: packed-u32 top-2 per row, per 128-code half of this 256-code tile.
    // wcol 0,1 cover block-local cols 0-63 / 64-127 of half 0; wcol 2,3 of half 1.
    uint32_t colc[4]; float se4[4];
    #pragma unroll
    for (int sn = 0; sn < 4; sn++) {
        const int cl = (wcol & 1) * 64 + sn * 16 + nl;   // 7-bit block-local col
        colc[sn] = (uint32_t)cl;
        se4[sn]  = sE[wcol * 64 + sn * 16 + nl];
    }
    #pragma unroll
    for (int sm = 0; sm < 4; sm++) {
        #pragma unroll
        for (int reg = 0; reg < 4; reg++) {
            const int rm = wrow * 64 + sm * 16 + qd * 4 + reg;
            const float zn = sZn[rm];
            uint32_t k0 = 0xFFFFFFFFu, k1 = 0xFFFFFFFFu;
            #pragma unroll
            for (int sn = 0; sn < 4; sn++) {
                const float v = fmaf(acc[sm][sn][reg], -0.03125f, zn + se4[sn]);
                const uint32_t key = (__float_as_uint(v) & 0xFFFFFF80u) | colc[sn];
                const uint32_t t1 = umax32(k0, key);
                k1 = umin32(k1, t1);
                k0 = umin32(k0, key);
            }
            #pragma unroll
            for (int msk = 1; msk <= 8; msk <<= 1) {
                const uint32_t o0 = (uint32_t)__shfl_xor((int)k0, msk, 64);
                const uint32_t o1 = (uint32_t)__shfl_xor((int)k1, msk, 64);
                const uint32_t n0 = umin32(k0, o0);
                k1 = umin32(umax32(k0, o0), umin32(k1, o1));
                k0 = n0;
            }
            if (nl == 0) { cK[wcol][rm].x = k0; cK[wcol][rm].y = k1; }
        }
    }
    __syncthreads();
    if (t < 512) {
        const int row = t & 255, h = t >> 8;
        const uint2 a = cK[2 * h][row], b = cK[2 * h + 1][row];
        uint2 r;
        r.x = umin32(a.x, b.x);
        r.y = umin32(umax32(a.x, b.x), umin32(a.y, b.y));
        pK[(size_t)(m0 + row) * NCB + blockIdx.x * 2 + h] = r;
    }
}

// ---------------- kernel 3: refine + gather + loss partials + histogram ----------------
// (round-0 verbatim — no fences, no fused finale)
__global__ __launch_bounds__(256)
void vq_gather_kernel(const float* __restrict__ z, const float* __restrict__ cb,
                      const float* __restrict__ znorm, const float* __restrict__ enorm,
                      const uint2* __restrict__ pK,
                      float* __restrict__ out_zq, float* __restrict__ out_idx,
                      int* __restrict__ counts, float* __restrict__ blockLoss) {
    const int lane = threadIdx.x & 63, wid = threadIdx.x >> 6;
    const int m = blockIdx.x * 4 + wid;

    uint32_t k0 = 0xFFFFFFFFu, k1 = 0xFFFFFFFFu;
    if (lane < NCB) {
        const uint2 kk = pK[(size_t)m * NCB + lane];
        k0 = kk.x; k1 = kk.y;
    }
    uint32_t g = k0;
    #pragma unroll
    for (int msk = 1; msk < 64; msk <<= 1) {
        const uint32_t o = (uint32_t)__shfl_xor((int)g, msk, 64);
        g = umin32(g, o);
    }
    const float gvf = __uint_as_float(g & 0xFFFFFF80u) + MARGIN;
    const bool f0 = (lane < NCB) && (__uint_as_float(k0 & 0xFFFFFF80u) <= gvf);
    const bool f1 = (lane < NCB) && (__uint_as_float(k1 & 0xFFFFFF80u) <= gvf);
    const unsigned long long b0 = __ballot(f0), b1 = __ballot(f1);
    int idx;
    if (__popcll(b0) + __popcll(b1) <= 1) {
        const unsigned long long bw = __ballot(k0 == g);
        idx = (int)__builtin_ctzll(bw) * 128 + (int)(g & 0x7Fu);
    } else {
        // exact fp32-lattice distance per candidate: d = fp32(fp32(zn+en) - 2*dot)
        const float zn = znorm[m];
        const float* zrow = z + (size_t)m * D_;
        float bestd = 1e30f; int besti = 0x7fffffff;
        #pragma unroll
        for (int slot = 0; slot < 2; slot++) {
            unsigned long long bm = slot ? b1 : b0;
            while (bm) {
                const int l = (int)__builtin_ctzll(bm); bm &= bm - 1;
                const uint32_t kx = (uint32_t)__shfl((int)(slot ? k1 : k0), l, 64);
                const int cand = l * 128 + (int)(kx & 0x7Fu);
                const float* crow = cb + (size_t)cand * D_;
                float s = 0.f;
                #pragma unroll
                for (int j = 0; j < 8; j++)
                    s += zrow[lane * 8 + j] * crow[lane * 8 + j];
                #pragma unroll
                for (int msk = 1; msk < 64; msk <<= 1) s += __shfl_xor(s, msk, 64);
                const float d = (zn + enorm[cand]) - 2.0f * s;
                if (lexlt(d, cand, bestd, besti)) { bestd = d; besti = cand; }
            }
        }
        idx = besti;
    }

    const float4* qrow  = (const float4*)(cb + (size_t)idx * D_);
    const float4* zrow4 = (const float4*)(z + (size_t)m * D_);
    float4*       orow  = (float4*)(out_zq + (size_t)m * D_);
    float lsum = 0.f;
    #pragma unroll
    for (int i = 0; i < 2; i++) {
        const int j = lane + i * 64;
        const float4 q  = qrow[j];
        const float4 zv = zrow4[j];
        float4 o;
        o.x = zv.x + (q.x - zv.x); o.y = zv.y + (q.y - zv.y);
        o.z = zv.z + (q.z - zv.z); o.w = zv.w + (q.w - zv.w);
        orow[j] = o;
        const float dx = zv.x - q.x, dy = zv.y - q.y, dz = zv.z - q.z, dw = zv.w - q.w;
        lsum += dx * dx + dy * dy + dz * dz + dw * dw;
    }
    #pragma unroll
    for (int msk = 1; msk < 64; msk <<= 1) lsum += __shfl_xor(lsum, msk, 64);

    if (lane == 0) {
        out_idx[m] = (float)idx;
        atomicAdd(&counts[idx], 1);
    }
    __shared__ float wl[4];
    if (lane == 0) wl[wid] = lsum;
    __syncthreads();
    if (threadIdx.x == 0) blockLoss[blockIdx.x] = wl[0] + wl[1] + wl[2] + wl[3];
}

// ---------------- kernel 4: scalars (loss, perplexity) ----------------
__global__ void vq_final_kernel(const int* __restrict__ counts,
                                const float* __restrict__ blockLoss,
                                float* __restrict__ out_loss, float* __restrict__ out_ppl) {
    __shared__ float sl[256], se[256];
    const int t = threadIdx.x;
    float ls = 0.f, es = 0.f;
    for (int i = t; i < N_ / 4; i += 256) ls += blockLoss[i];
    for (int k = t; k < K_; k += 256) {
        const float p = (float)counts[k] / (float)N_;
        es += p * logf(p + 1e-10f);
    }
    sl[t] = ls; se[t] = es;
    __syncthreads();
    for (int s = 128; s > 0; s >>= 1) {
        if (t < s) { sl[t] += sl[t + s]; se[t] += se[t + s]; }
        __syncthreads();
    }
    if (t == 0) {
        out_loss[0] = 0.25f * (sl[0] / (float)((size_t)N_ * D_));
        out_ppl[0]  = expf(-se[0]);
    }
}

extern "C" void kernel_launch(void* const* d_in, const int* in_sizes, int n_in,
                              void* d_out, int out_size, void* d_ws, size_t ws_size,
                              hipStream_t stream) {
    const float* z  = (const float*)d_in[0];
    const float* cb = (const float*)d_in[1];
    float* out = (float*)d_out;

    char* ws = (char*)d_ws;
    uint2*    pK        = (uint2*)   (ws + OFF_PK);
    float*    enorm     = (float*)   (ws + OFF_EN);
    float*    znorm     = (float*)   (ws + OFF_ZN);
    int*      counts    = (int*)     (ws + OFF_CNT);
    float*    blockLoss = (float*)   (ws + OFF_BL);
    _Float16* zh        = (_Float16*)(ws + OFF_ZH);
    _Float16* eh        = (_Float16*)(ws + OFF_EH);

    float* out_zq   = out;                         // [N_*D_]
    float* out_loss = out + (size_t)N_ * D_;       // [1]
    float* out_idx  = out_loss + 1;                // [N_]
    float* out_ppl  = out_idx + N_;                // [1]

    vq_prep_kernel<<<(N_ + K_) * 64 / 256, 256, 0, stream>>>(z, cb, zh, eh,
                                                             znorm, enorm, counts);

    dim3 grid(K_ / 256, N_ / 256);   // x = c-block fast: eh L2-resident
    vq_dist_kernel<<<grid, 1024, 0, stream>>>(zh, eh, enorm, znorm, pK);

    vq_gather_kernel<<<N_ / 4, 256, 0, stream>>>(z, cb, znorm, enorm, pK,
                                                 out_zq, out_idx, counts, blockLoss);

    vq_final_kernel<<<1, 256, 0, stream>>>(counts, blockLoss, out_loss, out_ppl);
}

// Round 9
// 203.954 us; speedup vs baseline: 1.0604x; 1.0604x over previous
//
#include <hip/hip_runtime.h>
#include <hip/hip_fp16.h>
#include <stdint.h>

#define B_  8
#define S_  2048
#define D_  512
#define K_  4096
#define N_  (B_ * S_)          // 16384 rows
#define NCB (K_ / 128)         // 32 code-blocks
#define NKB32 (D_ / 32)        // 16 k-blocks
#define MARGIN 0.014f          // 6sigma approx err + 127*ulp(512) key quantization

typedef _Float16 half8  __attribute__((ext_vector_type(8)));
typedef float    floatx4 __attribute__((ext_vector_type(4)));

// ---- workspace layout (bytes) ----
#define OFF_PK   0                                   // [N_][32] uint2 packed top-2 (4 MB)
#define OFF_EN   (OFF_PK + (size_t)N_ * NCB * 8)     // enorm [K_]
#define OFF_ZN   (OFF_EN + K_ * 4)                   // znorm [N_]
#define OFF_CNT  (OFF_ZN + N_ * 4)                   // counts [K_]
#define OFF_BL   (OFF_CNT + K_ * 4)                  // blockLoss [4096]
#define OFF_ZH   (OFF_BL + 4096 * 4)                 // zh packed [16][N_][32] f16 (16 MB)
#define OFF_EH   (OFF_ZH + (size_t)N_ * D_ * 2)      // eh packed [16][K_][32] f16 (4 MB)

__device__ __forceinline__ uint32_t umin32(uint32_t a, uint32_t b) { return a < b ? a : b; }
__device__ __forceinline__ uint32_t umax32(uint32_t a, uint32_t b) { return a > b ? a : b; }
__device__ __forceinline__ bool lexlt(float va, int ia, float vb, int ib) {
    return va < vb || (va == vb && ia < ib);
}

// async 16B global->LDS DMA; lds dst must be wave-uniform base + lane*16
__device__ __forceinline__ void load_lds16(const _Float16* g, _Float16* l) {
    __builtin_amdgcn_global_load_lds(
        (const __attribute__((address_space(1))) unsigned int*)(uintptr_t)g,
        (__attribute__((address_space(3))) unsigned int*)(uintptr_t)l,
        16, 0, 0);
}

// ---------------- kernel 1: fused prep ----------------
//  (a) row norms (order BIT-IDENTICAL across rounds -> preserves fp32 lattice),
//  (b) fp32->fp16 hi split, packed K-block-major + XOR chunk swizzle
//      (codebook scaled by 64, exact), (c) zero the histogram counts.
__global__ __launch_bounds__(256)
void vq_prep_kernel(const float* __restrict__ z, const float* __restrict__ cb,
                    _Float16* __restrict__ zh, _Float16* __restrict__ eh,
                    float* __restrict__ znorm, float* __restrict__ enorm,
                    int* __restrict__ counts) {
    const int t = threadIdx.x;
    if (blockIdx.x < 16) counts[blockIdx.x * 256 + t] = 0;

    const size_t u = (size_t)blockIdx.x * 256 + t;
    const int c   = (int)(u & 63);     // lane / chunk id (8 consecutive k)
    const int row = (int)(u >> 6);
    const bool isZ = row < N_;
    const int n = isZ ? row : row - N_;
    const float* r = (isZ ? z : cb) + (size_t)n * D_;

    // (a) norm — identical order across rounds
    float s = 0.f;
    for (int j = c; j < D_; j += 64) { float v = r[j]; s += v * v; }
    #pragma unroll
    for (int m = 1; m < 64; m <<= 1) s += __shfl_xor(s, m, 64);
    if (c == 0) { if (isZ) znorm[n] = s; else enorm[n] = s; }

    // (b) hi split
    const float scale = isZ ? 1.0f : 64.0f;
    const float4 v0 = *(const float4*)(r + c * 8);
    const float4 v1 = *(const float4*)(r + c * 8 + 4);
    float a[8] = {v0.x, v0.y, v0.z, v0.w, v1.x, v1.y, v1.z, v1.w};
    half8 h;
    #pragma unroll
    for (int j = 0; j < 8; j++) h[j] = (_Float16)(a[j] * scale);
    const int kb = c >> 2, qd = c & 3;
    const int sw = qd ^ ((n >> 1) & 3);
    const size_t rows = isZ ? (size_t)N_ : (size_t)K_;
    const size_t off = (size_t)kb * rows * 32 + (size_t)n * 32 + (size_t)(sw << 3);
    *(half8*)((isZ ? zh : eh) + off) = h;
}

// ---------------- kernel 2: approx distance GEMM + per-tile packed top-2 ----------------
// Best-measured configuration (round 6, total 200.0us): 128x128 tile, 4 waves,
// BK=64 (32 MFMA per barrier), A-tile double-buffer 2x16KB, B via registers.
// Session finding: MfmaUtil ~30-33% invariant across lockstep/barrier-free/
// BK32/BK64/256^2 structures -> latency/fabric plateau; this is the best cell.
__global__ __launch_bounds__(256, 4)
void vq_dist_kernel(const _Float16* __restrict__ zh, const _Float16* __restrict__ eh,
                    const float* __restrict__ enorm, const float* __restrict__ znorm,
                    uint2* __restrict__ pK) {
    __shared__ __align__(16) _Float16 sA[2][8192];   // 32 KB zh double-buffer (64-k tile)
    __shared__ float sE[128], sZn[128];
    __shared__ uint2 cK[2][128];

    const int t  = threadIdx.x;
    const int c0 = blockIdx.x * 128;   // x = c-fast: 4MB eh L2-resident
    const int m0 = blockIdx.y * 128;

    if (t < 128) { sE[t] = enorm[c0 + t]; sZn[t] = znorm[m0 + t]; }

    const int lane = t & 63, wid = t >> 6;
    const int wr = wid & 1, wc = wid >> 1;
    const int qd = lane >> 4, nl = lane & 15;
    const int sw8 = (qd ^ ((nl >> 1) & 3)) << 3;

    const size_t strideA = (size_t)N_ * 32;
    const size_t strideB = (size_t)K_ * 32;
    const _Float16* gsrc = zh + (size_t)m0 * 32 + (size_t)(wid * 2) * 512 + (size_t)lane * 8;
    const _Float16* bptr = eh + (size_t)c0 * 32 + (size_t)((wc * 64 + nl) * 32 + sw8);
    const int aoff = (wr * 64 + nl) * 32 + sw8;

    floatx4 acc[4][4];
    #pragma unroll
    for (int i = 0; i < 4; i++)
        #pragma unroll
        for (int j = 0; j < 4; j++) acc[i][j] = (floatx4)0.f;

    // stage one 64-k A-tile (2 kb-planes) into buffer b
    auto stageA = [&](int st, int b) {
        #pragma unroll
        for (int p = 0; p < 2; p++) {
            const _Float16* gk = gsrc + (size_t)(st * 2 + p) * strideA;
            _Float16* ld = sA[b] + p * 4096 + wid * 2 * 512;
            #pragma unroll
            for (int g = 0; g < 2; g++)
                load_lds16(gk + g * 512, ld + g * 512);
        }
    };

    stageA(0, 0);

    for (int st = 0; st < NKB32 / 2; st++) {   // 8 steps of BK=64
        __syncthreads();   // drains vmcnt: A-tile(st) landed; other buffer free
        if (st + 1 < NKB32 / 2) stageA(st + 1, (st + 1) & 1);

        #pragma unroll
        for (int p = 0; p < 2; p++) {          // two 32-k sub-steps, K-order preserved
            const _Float16* bp = bptr + (size_t)(st * 2 + p) * strideB;
            half8 b_h[4];
            #pragma unroll
            for (int s = 0; s < 4; s++)
                b_h[s] = *(const half8*)(bp + s * 512);
            const _Float16* ah = sA[st & 1] + p * 4096 + aoff;
            half8 a_h[4];
            #pragma unroll
            for (int s = 0; s < 4; s++)
                a_h[s] = *(const half8*)(ah + s * 512);
            #pragma unroll
            for (int i = 0; i < 4; i++)
                #pragma unroll
                for (int j = 0; j < 4; j++)
                    acc[i][j] = __builtin_amdgcn_mfma_f32_16x16x32_f16(a_h[i], b_h[j], acc[i][j], 0, 0, 0);
        }
    }

    // epilogue: packed-u32 top-2 per row over this 128-code block
    uint32_t colc[4]; float se4[4];
    #pragma unroll
    for (int sn = 0; sn < 4; sn++) {
        const int cl = wc * 64 + sn * 16 + nl;
        colc[sn] = (uint32_t)cl;          // 7-bit block-local col
        se4[sn]  = sE[cl];
    }
    #pragma unroll
    for (int sm = 0; sm < 4; sm++) {
        #pragma unroll
        for (int reg = 0; reg < 4; reg++) {
            const int rm = wr * 64 + sm * 16 + qd * 4 + reg;
            const float zn = sZn[rm];
            uint32_t k0 = 0xFFFFFFFFu, k1 = 0xFFFFFFFFu;
            #pragma unroll
            for (int sn = 0; sn < 4; sn++) {
                const float v = fmaf(acc[sm][sn][reg], -0.03125f, zn + se4[sn]);
                const uint32_t key = (__float_as_uint(v) & 0xFFFFFF80u) | colc[sn];
                const uint32_t t1 = umax32(k0, key);
                k1 = umin32(k1, t1);
                k0 = umin32(k0, key);
            }
            #pragma unroll
            for (int msk = 1; msk <= 8; msk <<= 1) {
                const uint32_t o0 = (uint32_t)__shfl_xor((int)k0, msk, 64);
                const uint32_t o1 = (uint32_t)__shfl_xor((int)k1, msk, 64);
                const uint32_t n0 = umin32(k0, o0);
                k1 = umin32(umax32(k0, o0), umin32(k1, o1));
                k0 = n0;
            }
            if (nl == 0) { cK[wc][rm].x = k0; cK[wc][rm].y = k1; }
        }
    }
    __syncthreads();
    if (t < 128) {
        const uint2 a = cK[0][t], b = cK[1][t];
        uint2 r;
        r.x = umin32(a.x, b.x);
        r.y = umin32(umax32(a.x, b.x), umin32(a.y, b.y));
        pK[(size_t)(m0 + t) * NCB + blockIdx.x] = r;
    }
}

// ---------------- kernel 3: refine + gather + loss partials + histogram ----------------
// (round-0 verbatim — no fences, no fused finale)
__global__ __launch_bounds__(256)
void vq_gather_kernel(const float* __restrict__ z, const float* __restrict__ cb,
                      const float* __restrict__ znorm, const float* __restrict__ enorm,
                      const uint2* __restrict__ pK,
                      float* __restrict__ out_zq, float* __restrict__ out_idx,
                      int* __restrict__ counts, float* __restrict__ blockLoss) {
    const int lane = threadIdx.x & 63, wid = threadIdx.x >> 6;
    const int m = blockIdx.x * 4 + wid;

    uint32_t k0 = 0xFFFFFFFFu, k1 = 0xFFFFFFFFu;
    if (lane < NCB) {
        const uint2 kk = pK[(size_t)m * NCB + lane];
        k0 = kk.x; k1 = kk.y;
    }
    uint32_t g = k0;
    #pragma unroll
    for (int msk = 1; msk < 64; msk <<= 1) {
        const uint32_t o = (uint32_t)__shfl_xor((int)g, msk, 64);
        g = umin32(g, o);
    }
    const float gvf = __uint_as_float(g & 0xFFFFFF80u) + MARGIN;
    const bool f0 = (lane < NCB) && (__uint_as_float(k0 & 0xFFFFFF80u) <= gvf);
    const bool f1 = (lane < NCB) && (__uint_as_float(k1 & 0xFFFFFF80u) <= gvf);
    const unsigned long long b0 = __ballot(f0), b1 = __ballot(f1);
    int idx;
    if (__popcll(b0) + __popcll(b1) <= 1) {
        const unsigned long long bw = __ballot(k0 == g);
        idx = (int)__builtin_ctzll(bw) * 128 + (int)(g & 0x7Fu);
    } else {
        // exact fp32-lattice distance per candidate: d = fp32(fp32(zn+en) - 2*dot)
        const float zn = znorm[m];
        const float* zrow = z + (size_t)m * D_;
        float bestd = 1e30f; int besti = 0x7fffffff;
        #pragma unroll
        for (int slot = 0; slot < 2; slot++) {
            unsigned long long bm = slot ? b1 : b0;
            while (bm) {
                const int l = (int)__builtin_ctzll(bm); bm &= bm - 1;
                const uint32_t kx = (uint32_t)__shfl((int)(slot ? k1 : k0), l, 64);
                const int cand = l * 128 + (int)(kx & 0x7Fu);
                const float* crow = cb + (size_t)cand * D_;
                float s = 0.f;
                #pragma unroll
                for (int j = 0; j < 8; j++)
                    s += zrow[lane * 8 + j] * crow[lane * 8 + j];
                #pragma unroll
                for (int msk = 1; msk < 64; msk <<= 1) s += __shfl_xor(s, msk, 64);
                const float d = (zn + enorm[cand]) - 2.0f * s;
                if (lexlt(d, cand, bestd, besti)) { bestd = d; besti = cand; }
            }
        }
        idx = besti;
    }

    const float4* qrow  = (const float4*)(cb + (size_t)idx * D_);
    const float4* zrow4 = (const float4*)(z + (size_t)m * D_);
    float4*       orow  = (float4*)(out_zq + (size_t)m * D_);
    float lsum = 0.f;
    #pragma unroll
    for (int i = 0; i < 2; i++) {
        const int j = lane + i * 64;
        const float4 q  = qrow[j];
        const float4 zv = zrow4[j];
        float4 o;
        o.x = zv.x + (q.x - zv.x); o.y = zv.y + (q.y - zv.y);
        o.z = zv.z + (q.z - zv.z); o.w = zv.w + (q.w - zv.w);
        orow[j] = o;
        const float dx = zv.x - q.x, dy = zv.y - q.y, dz = zv.z - q.z, dw = zv.w - q.w;
        lsum += dx * dx + dy * dy + dz * dz + dw * dw;
    }
    #pragma unroll
    for (int msk = 1; msk < 64; msk <<= 1) lsum += __shfl_xor(lsum, msk, 64);

    if (lane == 0) {
        out_idx[m] = (float)idx;
        atomicAdd(&counts[idx], 1);
    }
    __shared__ float wl[4];
    if (lane == 0) wl[wid] = lsum;
    __syncthreads();
    if (threadIdx.x == 0) blockLoss[blockIdx.x] = wl[0] + wl[1] + wl[2] + wl[3];
}

// ---------------- kernel 4: scalars (loss, perplexity) ----------------
__global__ void vq_final_kernel(const int* __restrict__ counts,
                                const float* __restrict__ blockLoss,
                                float* __restrict__ out_loss, float* __restrict__ out_ppl) {
    __shared__ float sl[256], se[256];
    const int t = threadIdx.x;
    float ls = 0.f, es = 0.f;
    for (int i = t; i < N_ / 4; i += 256) ls += blockLoss[i];
    for (int k = t; k < K_; k += 256) {
        const float p = (float)counts[k] / (float)N_;
        es += p * logf(p + 1e-10f);
    }
    sl[t] = ls; se[t] = es;
    __syncthreads();
    for (int s = 128; s > 0; s >>= 1) {
        if (t < s) { sl[t] += sl[t + s]; se[t] += se[t + s]; }
        __syncthreads();
    }
    if (t == 0) {
        out_loss[0] = 0.25f * (sl[0] / (float)((size_t)N_ * D_));
        out_ppl[0]  = expf(-se[0]);
    }
}

extern "C" void kernel_launch(void* const* d_in, const int* in_sizes, int n_in,
                              void* d_out, int out_size, void* d_ws, size_t ws_size,
                              hipStream_t stream) {
    const float* z  = (const float*)d_in[0];
    const float* cb = (const float*)d_in[1];
    float* out = (float*)d_out;

    char* ws = (char*)d_ws;
    uint2*    pK        = (uint2*)   (ws + OFF_PK);
    float*    enorm     = (float*)   (ws + OFF_EN);
    float*    znorm     = (float*)   (ws + OFF_ZN);
    int*      counts    = (int*)     (ws + OFF_CNT);
    float*    blockLoss = (float*)   (ws + OFF_BL);
    _Float16* zh        = (_Float16*)(ws + OFF_ZH);
    _Float16* eh        = (_Float16*)(ws + OFF_EH);

    float* out_zq   = out;                         // [N_*D_]
    float* out_loss = out + (size_t)N_ * D_;       // [1]
    float* out_idx  = out_loss + 1;                // [N_]
    float* out_ppl  = out_idx + N_;                // [1]

    vq_prep_kernel<<<(N_ + K_) * 64 / 256, 256, 0, stream>>>(z, cb, zh, eh,
                                                             znorm, enorm, counts);

    dim3 grid(K_ / 128, N_ / 128);   // x = c-block fast: eh L2-resident
    vq_dist_kernel<<<grid, 256, 0, stream>>>(zh, eh, enorm, znorm, pK);

    vq_gather_kernel<<<N_ / 4, 256, 0, stream>>>(z, cb, znorm, enorm, pK,
                                                 out_zq, out_idx, counts, blockLoss);

    vq_final_kernel<<<1, 256, 0, stream>>>(counts, blockLoss, out_loss, out_ppl);
}